// Round 3
// baseline (7296.027 us; speedup 1.0000x reference)
//
#include <hip/hip_runtime.h>
#include <hip/hip_bf16.h>

#define T_STEPS 512
#define BATCH 64
#define TB (T_STEPS * BATCH)   // 32768

typedef short bf16x8 __attribute__((ext_vector_type(8)));
typedef float f32x4 __attribute__((ext_vector_type(4)));

union FragU { uint4 u; bf16x8 v; };

static __device__ __forceinline__ bf16x8 ld_frag(const uint4* p) {
  FragU f; f.u = *p; return f.v;
}

static __device__ __forceinline__ unsigned short f2bf(float f) {
  unsigned u = __float_as_uint(f);
  return (unsigned short)((u + 0x7FFFu + ((u >> 16) & 1u)) >> 16);
}

static __device__ __forceinline__ int revrow(int r) {
  int t = r >> 6, b = r & 63;
  return ((T_STEPS - 1 - t) << 6) | b;
}

#define S_RZ  (-1.4426950408889634f)   /* -log2(e)   : sigmoid(p)=1/(1+2^(S_RZ*p)) */
#define S_C   (-2.8853900817779268f)   /* -2*log2(e) : tanh(p)=2/(1+2^(S_C*p))-1   */

// ---------------- pack weights into MFMA B-fragment layout (with gate pre-scaling) ----
// modes: 0 = X3 (768 cols, order [r|cand|z], g=n>>8), 1 = RZ (512 cols, g=n<256?0:2), 2 = C (256 cols, g=1)
__global__ void pack_w_kernel(const float* __restrict__ W, int rows, int k_base,
                              int n_tiles, int k_tiles, int mode,
                              unsigned short* __restrict__ dst) {
  int gid = blockIdx.x * blockDim.x + threadIdx.x;
  int total = n_tiles * k_tiles * 64;
  if (gid >= total) return;
  int lane = gid & 63;
  int fi = gid >> 6;
  int kt = fi % k_tiles;
  int nt = fi / k_tiles;
  int n = nt * 16 + (lane & 15);
  int g, col; float s;
  if (mode == 0)      { g = n >> 8;            col = n & 255; s = (g == 1) ? S_C : S_RZ; }
  else if (mode == 1) { g = (n < 256) ? 0 : 2; col = n & 255; s = S_RZ; }
  else                { g = 1;                 col = n;       s = S_C; }
  int k0 = k_base + kt * 32 + ((lane >> 4) << 3);
  const float* src = W + ((size_t)g * rows + k0) * 256 + col;
  unsigned short v[8];
#pragma unroll
  for (int j = 0; j < 8; ++j) v[j] = f2bf(src[(size_t)j * 256] * s);
  uint4 o;
  o.x = v[0] | ((unsigned)v[1] << 16);
  o.y = v[2] | ((unsigned)v[3] << 16);
  o.z = v[4] | ((unsigned)v[5] << 16);
  o.w = v[6] | ((unsigned)v[7] << 16);
  ((uint4*)dst)[gid] = o;
}

static __device__ __forceinline__ bf16x8 cvt8(float4 f0, float4 f1) {
  uint4 o;
  o.x = f2bf(f0.x) | ((unsigned)f2bf(f0.y) << 16);
  o.y = f2bf(f0.z) | ((unsigned)f2bf(f0.w) << 16);
  o.z = f2bf(f1.x) | ((unsigned)f2bf(f1.y) << 16);
  o.w = f2bf(f1.z) | ((unsigned)f2bf(f1.w) << 16);
  FragU f; f.u = o; return f.v;
}

// ---------------- Xg GEMM (chunked): writes C-fragment subtile layout ------------------
// Xg layout per dir: [rt8 = chunkT*8][ct = 48][slot = 32] of f32x4
//   (slot,reg): row_within_8 = (slot>>4)*4 + reg, col = (slot&15);  ct*16+col = Xg column
template<int LAYER>
__global__ __launch_bounds__(256)
void gemm_xg_kernel(const float* __restrict__ x,
                    const unsigned short* __restrict__ fs0,
                    const unsigned short* __restrict__ bs0,
                    const unsigned short* __restrict__ Bp,
                    const float* __restrict__ bias_fw,
                    const float* __restrict__ bias_bw,
                    f32x4* __restrict__ Xg, int t0, int chunkT)
{
  constexpr int KT = (LAYER == 0) ? 8 : 16;
  int dir = blockIdx.z;
  int lane = threadIdx.x & 63;
  int w = threadIdx.x >> 6;
  int ww = w >> 1, wc = w & 1;
  int mt0 = blockIdx.x * 8 + ww * 4;
  int nt0 = blockIdx.y * 8 + wc * 4;
  const uint4* B = (const uint4*)Bp + (size_t)dir * 48 * KT * 64;
  const int arow = lane & 15;
  const int k0b = ((lane >> 4) << 3);

  f32x4 acc[4][4] = {};
#pragma unroll
  for (int kt = 0; kt < KT; ++kt) {
    int k0 = kt * 32 + k0b;
    bf16x8 a[4], b[4];
#pragma unroll
    for (int i = 0; i < 4; ++i) {
      int grow = t0 * 64 + (mt0 + i) * 16 + arow;
      if (LAYER == 0) {
        int gr = dir ? revrow(grow) : grow;
        const float4* s = (const float4*)(x + (size_t)gr * 256 + k0);
        a[i] = cvt8(s[0], s[1]);
      } else {
        const unsigned short* base; int r2 = grow, kk = k0;
        if (k0 < 256) { base = dir ? bs0 : fs0; }
        else          { base = dir ? fs0 : bs0; r2 = revrow(grow); kk = k0 - 256; }
        a[i] = *(const bf16x8*)(base + (size_t)r2 * 256 + kk);
      }
    }
#pragma unroll
    for (int j = 0; j < 4; ++j) b[j] = ld_frag(B + ((size_t)(nt0 + j) * KT + kt) * 64 + lane);
#pragma unroll
    for (int i = 0; i < 4; ++i)
#pragma unroll
      for (int j = 0; j < 4; ++j)
        acc[i][j] = __builtin_amdgcn_mfma_f32_16x16x32_bf16(a[i], b[j], acc[i][j], 0, 0, 0);
  }

  const float* bias = dir ? bias_bw : bias_fw;
  f32x4* C = Xg + (size_t)dir * chunkT * 8 * 48 * 32;
  const int slot = lane & 31;
  const int rthalf = lane >> 5;          // 0: rows 0-7 of tile, 1: rows 8-15
#pragma unroll
  for (int j = 0; j < 4; ++j) {
    int ct = nt0 + j;
    int col = ct * 16 + (lane & 15);
    int g = col >> 8, cc = col & 255;
    float bv = ((g == 1) ? S_C : S_RZ) * bias[g * 256 + cc];
#pragma unroll
    for (int i = 0; i < 4; ++i) {
      int R = blockIdx.x * 128 + ww * 64 + i * 16;      // chunk-local row
      int rt8 = (R >> 3) + rthalf;
      f32x4 v = acc[i][j];
      v[0] += bv; v[1] += bv; v[2] += bv; v[3] += bv;
      C[((size_t)rt8 * 48 + ct) * 32 + slot] = v;
    }
  }
}

// ---------------- persistent recurrent GRU kernel (one layer, both dirs, chunked) -----
// grid (8, 2): blockIdx.x = 8-row batch block, blockIdx.y = dir. 512 threads = 8 waves.
// Weights resident in VGPRs (192); h/rh in XOR-swizzled LDS (rows 8-15 zero padding).
template<int LAYER>
__global__ __launch_bounds__(512, 2)
void gru_kernel(const f32x4* __restrict__ Xg,
                const uint4* __restrict__ whrz_fw, const uint4* __restrict__ whrz_bw, // [32][8][64]
                const uint4* __restrict__ whcA_fw, const uint4* __restrict__ whcA_bw, // [16][8][64]
                unsigned short* __restrict__ sfw_bf, unsigned short* __restrict__ sbw_bf,
                float* __restrict__ out,
                float* __restrict__ hstate, float* __restrict__ dout_h,
                int t0, int chunkT)
{
  const int dir = blockIdx.y;
  const int bx = blockIdx.x;
  const int row0 = bx * 8;
  const int tid = threadIdx.x;
  const int lane = tid & 63;
  const int w = tid >> 6;

  __shared__ __align__(16) unsigned short h_bf[16 * 256];   // swizzled, rows 8-15 = 0
  __shared__ __align__(16) unsigned short rh_bf[16 * 256];  // swizzled, rows 8-15 = 0
  __shared__ __align__(16) float h_f[8 * 256];
  __shared__ __align__(16) float z_f[8 * 256];

  const uint4* whrzp = dir ? whrz_bw : whrz_fw;
  const uint4* whcp  = dir ? whcA_bw : whcA_fw;

  bf16x8 wrz[4][8], whc[2][8];
#pragma unroll
  for (int nt = 0; nt < 4; ++nt)
#pragma unroll
    for (int kt = 0; kt < 8; ++kt)
      wrz[nt][kt] = ld_frag(whrzp + ((size_t)(w * 4 + nt) * 8 + kt) * 64 + lane);
#pragma unroll
  for (int nt = 0; nt < 2; ++nt)
#pragma unroll
    for (int kt = 0; kt < 8; ++kt)
      whc[nt][kt] = ld_frag(whcp + ((size_t)(w * 2 + nt) * 8 + kt) * 64 + lane);

  float* hst = hstate + (size_t)(dir * 8 + bx) * 2048;
  // zero pad rows 8-15 of both bf16 buffers
  for (int i = 2048 + tid; i < 4096; i += 512) { h_bf[i] = 0; rh_bf[i] = 0; }
  // init rows 0-7
  for (int i = tid; i < 8 * 256; i += 512) {
    float v = (t0 == 0) ? 0.0f : hst[i];
    h_f[i] = v;
    int rr = i >> 8, cc = i & 255;
    int cb = cc * 2;
    int byt = rr * 512 + (((cb & ~15) ^ ((rr & 7) << 4)) | (cb & 15));
    *(unsigned short*)((char*)h_bf + byt) = f2bf(v);
  }
  __syncthreads();

  const int ccol = lane & 15;
  const int crow = ((lane >> 4) << 2);     // 0,4,8,12 (valid rows: crow<8 i.e. lane<32)
  const bool lo = (lane < 32);
  const bool is_r = (w < 4);
  const int slot = lane & 31;
  const f32x4* XgD = Xg + (size_t)dir * chunkT * 8 * 48 * 32;
  unsigned short* sp_bf = dir ? sbw_bf : sfw_bf;
  const int coff = dir ? 256 : 0;
  // A-frag LDS read address (swizzled): row = lane&15
  const int ardbase = (lane & 15) * 512;
  const int arxor = ((lane & 7) << 4);     // (afrow&7)<<4 since afrow=lane&15, &7 == lane&7
  const int afc = ((lane >> 4) << 4);

  // Xg col-tiles this thread reads
  const int ctA0 = (w * 4 + 0) + (is_r ? 0 : 16);
  const int ctB0 = 16 + w * 2;

  // prefetch phase-A xg for first step
  size_t tb0 = ((size_t)(0 * 8 + bx) * 48) * 32 + slot;
  f32x4 a0 = XgD[tb0 + (size_t)(ctA0 + 0) * 32];
  f32x4 a1 = XgD[tb0 + (size_t)(ctA0 + 1) * 32];
  f32x4 a2 = XgD[tb0 + (size_t)(ctA0 + 2) * 32];
  f32x4 a3 = XgD[tb0 + (size_t)(ctA0 + 3) * 32];

#pragma unroll 1
  for (int t = t0; t < t0 + chunkT; ++t) {
    const int tloc = t - t0;
    // ---------- phase A: rz = h @ Whrz (+x-part) ----------
    f32x4 acc0 = {}, acc1 = {}, acc2 = {}, acc3 = {};
#pragma unroll
    for (int kt = 0; kt < 8; ++kt) {
      int byt = ardbase + ((kt * 64 + afc) ^ arxor);
      bf16x8 a = *(const bf16x8*)((const char*)h_bf + byt);
      acc0 = __builtin_amdgcn_mfma_f32_16x16x32_bf16(a, wrz[0][kt], acc0, 0, 0, 0);
      acc1 = __builtin_amdgcn_mfma_f32_16x16x32_bf16(a, wrz[1][kt], acc1, 0, 0, 0);
      acc2 = __builtin_amdgcn_mfma_f32_16x16x32_bf16(a, wrz[2][kt], acc2, 0, 0, 0);
      acc3 = __builtin_amdgcn_mfma_f32_16x16x32_bf16(a, wrz[3][kt], acc3, 0, 0, 0);
    }
    // issue phase-B xg loads for this step (consumed after phase-B MFMA)
    size_t tbc = ((size_t)(tloc * 8 + bx) * 48) * 32 + slot;
    f32x4 b0 = XgD[tbc + (size_t)(ctB0 + 0) * 32];
    f32x4 b1 = XgD[tbc + (size_t)(ctB0 + 1) * 32];
#pragma unroll
    for (int nt = 0; nt < 4; ++nt) {
      f32x4 xv = (nt == 0) ? a0 : (nt == 1) ? a1 : (nt == 2) ? a2 : a3;
      f32x4 ac = (nt == 0) ? acc0 : (nt == 1) ? acc1 : (nt == 2) ? acc2 : acc3;
      int cl = (w * 4 + nt) * 16 + ccol;
#pragma unroll
      for (int r = 0; r < 4; ++r) {
        float v = ac[r] + xv[r];
        float gate = __builtin_amdgcn_rcpf(1.0f + __builtin_amdgcn_exp2f(v)); // sigmoid
        if (lo) {
          int rr = crow + r;
          if (is_r) {
            float h = h_f[rr * 256 + cl];
            int cb = cl * 2;
            int byt = rr * 512 + (((cb & ~15) ^ ((rr & 7) << 4)) | (cb & 15));
            *(unsigned short*)((char*)rh_bf + byt) = f2bf(gate * h);
          } else {
            z_f[rr * 256 + (cl - 256)] = gate;
          }
        }
      }
    }
    asm volatile("s_waitcnt lgkmcnt(0)" ::: "memory");
    __builtin_amdgcn_s_barrier();

    // ---------- phase B: cand = tanh-form((r*h) @ Whc + x-part), update h ----------
    f32x4 acc4 = {}, acc5 = {};
#pragma unroll
    for (int kt = 0; kt < 8; ++kt) {
      int byt = ardbase + ((kt * 64 + afc) ^ arxor);
      bf16x8 a = *(const bf16x8*)((const char*)rh_bf + byt);
      acc4 = __builtin_amdgcn_mfma_f32_16x16x32_bf16(a, whc[0][kt], acc4, 0, 0, 0);
      acc5 = __builtin_amdgcn_mfma_f32_16x16x32_bf16(a, whc[1][kt], acc5, 0, 0, 0);
    }
    // prefetch phase-A xg for next step (in flight across the raw barrier)
    int tn = (tloc + 1 < chunkT) ? tloc + 1 : tloc;
    size_t tbn = ((size_t)(tn * 8 + bx) * 48) * 32 + slot;
    a0 = XgD[tbn + (size_t)(ctA0 + 0) * 32];
    a1 = XgD[tbn + (size_t)(ctA0 + 1) * 32];
    a2 = XgD[tbn + (size_t)(ctA0 + 2) * 32];
    a3 = XgD[tbn + (size_t)(ctA0 + 3) * 32];

    int gbase = (LAYER == 1 && dir) ? ((T_STEPS - 1 - t) * 64 + row0) : (t * 64 + row0);
#pragma unroll
    for (int nt = 0; nt < 2; ++nt) {
      f32x4 xv = (nt == 0) ? b0 : b1;
      f32x4 ac = (nt == 0) ? acc4 : acc5;
      int c2 = (w * 2 + nt) * 16 + ccol;
#pragma unroll
      for (int r = 0; r < 4; ++r) {
        float v = ac[r] + xv[r];
        float cand = __builtin_amdgcn_rcpf(1.0f + __builtin_amdgcn_exp2f(v)) * 2.0f - 1.0f;
        if (lo) {
          int rr = crow + r;
          float z = z_f[rr * 256 + c2];
          float h = h_f[rr * 256 + c2];
          float hn = cand + z * (h - cand);
          h_f[rr * 256 + c2] = hn;
          int cb = c2 * 2;
          int byt = rr * 512 + (((cb & ~15) ^ ((rr & 7) << 4)) | (cb & 15));
          *(unsigned short*)((char*)h_bf + byt) = f2bf(hn);
          if (LAYER == 0) sp_bf[(size_t)(gbase + rr) * 256 + c2] = f2bf(hn);
          else            out[(size_t)(gbase + rr) * 512 + coff + c2] = hn;
        }
      }
    }
    asm volatile("s_waitcnt lgkmcnt(0)" ::: "memory");
    __builtin_amdgcn_s_barrier();
  }

  // persist h; on last chunk also write fh/bh
  for (int i = tid; i < 8 * 256; i += 512) hst[i] = h_f[i];
  if (t0 + chunkT == T_STEPS) {
    float* dst = dout_h + (dir ? 32768 : 0) + (size_t)LAYER * 16384;
    for (int i = tid; i < 8 * 256; i += 512) {
      int rr = i >> 8, cc = i & 255;
      dst[(size_t)(row0 + rr) * 256 + cc] = h_f[i];
    }
  }
}

__global__ void diag_kernel(float* out, float v) { out[0] = v; }

// --------------------------------------------------------------------------------------
extern "C" void kernel_launch(void* const* d_in, const int* in_sizes, int n_in,
                              void* d_out, int out_size, void* d_ws, size_t ws_size,
                              hipStream_t stream) {
  const float* x     = (const float*)d_in[0];
  const float* fw_W0 = (const float*)d_in[2];
  const float* fw_b0 = (const float*)d_in[3];
  const float* fw_W1 = (const float*)d_in[4];
  const float* fw_b1 = (const float*)d_in[5];
  const float* bw_W0 = (const float*)d_in[6];
  const float* bw_b0 = (const float*)d_in[7];
  const float* bw_W1 = (const float*)d_in[8];
  const float* bw_b1 = (const float*)d_in[9];

  char* ws = (char*)d_ws;
  size_t off = 0;
  auto alloc = [&](size_t bytes) -> char* {
    char* p = ws + off; off += (bytes + 255) & ~(size_t)255; return p;
  };
  unsigned short* Wx0p  = (unsigned short*)alloc(2ull * 48 * 8 * 64 * 8 * 2);
  unsigned short* Wx1p  = (unsigned short*)alloc(2ull * 48 * 16 * 64 * 8 * 2);
  unsigned short* Whrz0 = (unsigned short*)alloc(2ull * 32 * 8 * 64 * 8 * 2);
  unsigned short* Whc0  = (unsigned short*)alloc(2ull * 16 * 8 * 64 * 8 * 2);
  unsigned short* Whrz1 = (unsigned short*)alloc(2ull * 32 * 8 * 64 * 8 * 2);
  unsigned short* Whc1  = (unsigned short*)alloc(2ull * 16 * 8 * 64 * 8 * 2);
  unsigned short* fs0   = (unsigned short*)alloc((size_t)TB * 256 * 2);
  unsigned short* bs0   = (unsigned short*)alloc((size_t)TB * 256 * 2);
  float* hstate         = (float*)alloc(2ull * 8 * 8 * 256 * 4);

  // pick largest time-chunk (<=128 for L3 residency) whose Xg buffer fits
  int chunkT = 0;
  for (int ct = 128; ct >= 8; ct >>= 1) {
    if (off + (size_t)ct * 2 * 64 * 768 * 4 <= ws_size) { chunkT = ct; break; }
  }
  float* out = (float*)d_out;
  if (chunkT == 0) {
    diag_kernel<<<1, 1, 0, stream>>>(out, 12345.0f);
    return;
  }
  f32x4* Xg = (f32x4*)alloc((size_t)chunkT * 2 * 64 * 768 * 4);
  float* dout_h = out + (size_t)TB * 512;

  auto packw = [&](const float* W, int rows, int kb, int ntl, int ktl, int mode, unsigned short* dst) {
    int total = ntl * ktl * 64;
    pack_w_kernel<<<(total + 255) / 256, 256, 0, stream>>>(W, rows, kb, ntl, ktl, mode, dst);
  };
  packw(fw_W0, 512, 0,   48, 8,  0, Wx0p);
  packw(bw_W0, 512, 0,   48, 8,  0, Wx0p + 48 * 8 * 64 * 8);
  packw(fw_W1, 768, 0,   48, 16, 0, Wx1p);
  packw(bw_W1, 768, 0,   48, 16, 0, Wx1p + 48 * 16 * 64 * 8);
  packw(fw_W0, 512, 256, 32, 8,  1, Whrz0);
  packw(bw_W0, 512, 256, 32, 8,  1, Whrz0 + 32 * 8 * 64 * 8);
  packw(fw_W0, 512, 256, 16, 8,  2, Whc0);
  packw(bw_W0, 512, 256, 16, 8,  2, Whc0 + 16 * 8 * 64 * 8);
  packw(fw_W1, 768, 512, 32, 8,  1, Whrz1);
  packw(bw_W1, 768, 512, 32, 8,  1, Whrz1 + 32 * 8 * 64 * 8);
  packw(fw_W1, 768, 512, 16, 8,  2, Whc1);
  packw(bw_W1, 768, 512, 16, 8,  2, Whc1 + 16 * 8 * 64 * 8);

  dim3 rgrid(8, 2);
  // layer 0
  for (int t0 = 0; t0 < T_STEPS; t0 += chunkT) {
    dim3 ggrid(chunkT * 64 / 128, 6, 2);
    gemm_xg_kernel<0><<<ggrid, 256, 0, stream>>>(x, nullptr, nullptr, Wx0p, fw_b0, bw_b0, Xg, t0, chunkT);
    gru_kernel<0><<<rgrid, 512, 0, stream>>>(Xg,
        (const uint4*)Whrz0, (const uint4*)(Whrz0 + 32 * 8 * 64 * 8),
        (const uint4*)Whc0,  (const uint4*)(Whc0 + 16 * 8 * 64 * 8),
        fs0, bs0, nullptr, hstate, dout_h, t0, chunkT);
  }
  // layer 1
  for (int t0 = 0; t0 < T_STEPS; t0 += chunkT) {
    dim3 ggrid(chunkT * 64 / 128, 6, 2);
    gemm_xg_kernel<1><<<ggrid, 256, 0, stream>>>(nullptr, fs0, bs0, Wx1p, fw_b1, bw_b1, Xg, t0, chunkT);
    gru_kernel<1><<<rgrid, 512, 0, stream>>>(Xg,
        (const uint4*)Whrz1, (const uint4*)(Whrz1 + 32 * 8 * 64 * 8),
        (const uint4*)Whc1,  (const uint4*)(Whc1 + 16 * 8 * 64 * 8),
        nullptr, nullptr, out, hstate, dout_h, t0, chunkT);
  }
}